// Round 5
// baseline (6743.159 us; speedup 1.0000x reference)
//
#include <hip/hip_runtime.h>
#include <stdint.h>

// PoseRNN: fused = cat(fv,fi) -> 2-layer GRU(768) -> Linear(768,128)+LeakyReLU(0.1) -> Linear(128,6)
// Persistent pipelined 2-layer GRU: 257 rounds, 192 WGs = 48 slices x 2 layers x 2 batch halves.
// Round-3: back to round-1's PROVEN coherence protocol (threadfence release + ACQ_REL arrive,
// acquire at exit), no inline asm anywhere. Changes vs round 1:
//   (a) spin polls are RELAXED (agent) with every-16th ACQUIRE + one acquire fence at exit
//       -> kills the per-poll buffer_inv storm that made each round 17.5us
//   (b) WROW 776->772 + B fragments via two ds_read_b64 -> 4 lanes/bank = wave64 b64 floor
//       (round 1: 8-way conflicts, 6.3e7 SQ_LDS_BANK_CONFLICT)
//   (c) all 24 A-fragments issued before the MFMA loop -> one miss-latency, not six serial

typedef __attribute__((ext_vector_type(8))) short bf16x8;   // 8 bf16 in 4 VGPRs
typedef __attribute__((ext_vector_type(4))) short bf16x4;   // 8B
typedef __attribute__((ext_vector_type(4))) float f32x4;

#define H_   768
#define TH3  2304
#define BATCH 64
#define SEQ  256
#define SLAB (BATCH * H_)   /* 49152 elems, one timestep of h/y for all batches */
#define WROW 772            /* padded LDS row stride (ushorts): start bank 2*n16+4*kg */
#define NWG_GROUP 96        /* WGs per barrier group (48 slices x 2 layers) */
#define CNT_STRIDE 32       /* ints per round-counter (128B line) */

__device__ __forceinline__ uint16_t f2b(float f) {
  union { float f; uint32_t u; } v; v.f = f;
  uint32_t u = v.u;
  return (uint16_t)((u + 0x7FFFu + ((u >> 16) & 1u)) >> 16);  // RNE
}

__device__ __forceinline__ f32x4 mfma16(bf16x8 a, bf16x8 b, f32x4 c) {
  return __builtin_amdgcn_mfma_f32_16x16x32_bf16(a, b, c, 0, 0, 0);
}

__device__ __forceinline__ bf16x8 ldB(const uint16_t* p) {   // two ds_read_b64 (8B-aligned rows)
  bf16x4 lo = *reinterpret_cast<const bf16x4*>(p);
  bf16x4 hi = *reinterpret_cast<const bf16x4*>(p + 4);
  bf16x8 r;
  r[0] = lo[0]; r[1] = lo[1]; r[2] = lo[2]; r[3] = lo[3];
  r[4] = hi[0]; r[5] = hi[1]; r[6] = hi[2]; r[7] = hi[3];
  return r;
}

// ---------------- prep: build time-major bf16 X, zero h0 slabs + counters, bf16 W1 -------------
__global__ __launch_bounds__(256) void prep_kernel(
    const float* __restrict__ fv, const float* __restrict__ fi,
    const float* __restrict__ W1,
    uint16_t* __restrict__ Xbf, uint16_t* __restrict__ Y0, uint16_t* __restrict__ Y1,
    int* __restrict__ cnts, uint16_t* __restrict__ W1b)
{
  const int NX = SEQ * SLAB;          // 12,582,912
  const int NY = SLAB;
  const int NC = 2 * 257 * CNT_STRIDE;
  const int NW = 128 * H_;
  const int total = NX + 2 * NY + NC + NW;
  for (int idx = blockIdx.x * blockDim.x + threadIdx.x; idx < total;
       idx += gridDim.x * blockDim.x) {
    if (idx < NX) {
      int s = idx / SLAB;
      int rem = idx - s * SLAB;
      int b = rem / H_;
      int h = rem - b * H_;
      float val = (h < 512) ? fv[((size_t)b * SEQ + s) * 512 + h]
                            : fi[((size_t)b * SEQ + s) * 256 + (h - 512)];
      Xbf[idx] = f2b(val);
    } else if (idx < NX + 2 * NY) {
      int k = idx - NX;
      if (k < NY) Y0[k] = 0; else Y1[k - NY] = 0;
    } else if (idx < NX + 2 * NY + NC) {
      cnts[idx - NX - 2 * NY] = 0;
    } else {
      int k = idx - NX - 2 * NY - NC;
      W1b[k] = f2b(W1[k]);
    }
  }
}

// ---------------- persistent pipelined 2-layer GRU ----------------
__global__ __launch_bounds__(256) void gru_persist(
    const float* __restrict__ Wih, const float* __restrict__ Whh,
    const float* __restrict__ bih, const float* __restrict__ bhh,
    const uint16_t* __restrict__ Xbf, uint16_t* __restrict__ Y0, uint16_t* __restrict__ Y1,
    int* __restrict__ cnts, float* __restrict__ out_hn)
{
  __shared__ __attribute__((aligned(16))) uint16_t Wx[48 * WROW];  // 74,112 B
  __shared__ __attribute__((aligned(16))) uint16_t Wh[48 * WROW];  // 74,112 B
  __shared__ float ghbuf[32 * 48];                                 //  6,144 B
  __shared__ float hmast[32 * 16];                                 //  2,048 B
  __shared__ float bI[48];
  __shared__ float bH[48];

  const int bid   = blockIdx.x;        // 0..191
  const int slice = bid % 48;          // hidden slice: units [slice*16, slice*16+16)
  const int layer = (bid / 48) & 1;    // 0 or 1
  const int bhalf = bid / 96;          // batch half (barrier group)
  const int tid  = threadIdx.x;
  const int lane = tid & 63;
  const int wid  = tid >> 6;           // 4 waves
  const int mblk = wid & 1;            // 16-batch sub-block within the 32-batch half
  const int isGh = wid >> 1;           // waves 0,1 -> x-GEMM (+combine); waves 2,3 -> h-GEMM
  const int n16  = lane & 15;
  const int kg   = lane >> 4;

  // --- one-time: weight slices -> LDS bf16; rows ordered [r(16) z(16) n(16)] ---
  const float* wx_g = Wih + (size_t)layer * TH3 * H_;
  const float* wh_g = Whh + (size_t)layer * TH3 * H_;
  for (int idx = tid; idx < 48 * H_; idx += 256) {
    int lr = idx / H_;
    int c  = idx - lr * H_;
    int gate = lr >> 4, j = lr & 15;
    size_t grow = (size_t)(gate * H_ + slice * 16 + j);
    Wx[lr * WROW + c] = f2b(wx_g[grow * H_ + c]);
    Wh[lr * WROW + c] = f2b(wh_g[grow * H_ + c]);
  }
  if (tid < 48) {
    int gate = tid >> 4, j = tid & 15;
    bI[tid] = bih[layer * TH3 + gate * H_ + slice * 16 + j];
    bH[tid] = bhh[layer * TH3 + gate * H_ + slice * 16 + j];
  }
  for (int idx = tid; idx < 32 * 16; idx += 256) hmast[idx] = 0.0f;
  __syncthreads();

  const int batch0 = bhalf * 32;
  int* mycnt = cnts + (size_t)bhalf * 257 * CNT_STRIDE;
  uint16_t* Yown = layer ? Y1 : Y0;

  for (int r = 0; r <= 256; ++r) {
    const bool active = (layer == 0) ? (r < 256) : (r >= 1);
    f32x4 acc0 = {0,0,0,0}, acc1 = {0,0,0,0}, acc2 = {0,0,0,0};
    uint16_t* dst = nullptr;

    if (active) {
      // layer0 step t=r:   x=Xbf[r],  h=Y0[r],   writes Y0[r+1]
      // layer1 step t=r-1: x=Y0[r],   h=Y1[r-1], writes Y1[r]
      const uint16_t* xs = (layer == 0) ? (Xbf + (size_t)r * SLAB) : (Y0 + (size_t)r * SLAB);
      const uint16_t* hs = (layer == 0) ? (Y0 + (size_t)r * SLAB) : (Y1 + (size_t)(r - 1) * SLAB);
      dst = Yown + (size_t)((layer == 0) ? (r + 1) : r) * SLAB;

      const uint16_t* A  = (isGh ? hs : xs) + (size_t)(batch0 + mblk * 16) * H_;
      const uint16_t* ap = A + (size_t)n16 * H_ + kg * 8;
      const uint16_t* Wl = isGh ? Wh : Wx;
      const uint16_t* bp = Wl + (size_t)n16 * WROW + kg * 8;

      // ---- A-operand: issue all 24 16B loads up front; one miss-latency instead of six ----
      bf16x8 afr[24];
      #pragma unroll
      for (int ks = 0; ks < 24; ++ks)
        afr[ks] = *reinterpret_cast<const bf16x8*>(ap + ks * 32);

      #pragma unroll 4
      for (int ks = 0; ks < 24; ++ks) {
        bf16x8 av  = afr[ks];
        bf16x8 bv0 = ldB(bp + ks * 32);
        bf16x8 bv1 = ldB(bp + 16 * WROW + ks * 32);
        bf16x8 bv2 = ldB(bp + 32 * WROW + ks * 32);
        acc0 = mfma16(av, bv0, acc0);
        acc1 = mfma16(av, bv1, acc1);
        acc2 = mfma16(av, bv2, acc2);
      }
      if (isGh) {
        #pragma unroll
        for (int q = 0; q < 4; ++q) {
          int bi = mblk * 16 + 4 * kg + q;          // D row = 4*(lane>>4)+q
          ghbuf[bi * 48 +      n16] = acc0[q];
          ghbuf[bi * 48 + 16 + n16] = acc1[q];
          ghbuf[bi * 48 + 32 + n16] = acc2[q];
        }
      }
    }
    __syncthreads();  // gh tiles visible to combine waves

    if (active && !isGh) {
      const bool lastStep = (layer == 0) ? (r == 255) : (r == 256);
      #pragma unroll
      for (int q = 0; q < 4; ++q) {
        int bi = mblk * 16 + 4 * kg + q;
        float ghr = ghbuf[bi * 48 +      n16] + bH[n16];
        float ghz = ghbuf[bi * 48 + 16 + n16] + bH[16 + n16];
        float ghn = ghbuf[bi * 48 + 32 + n16] + bH[32 + n16];
        float gxr = acc0[q] + bI[n16];
        float gxz = acc1[q] + bI[16 + n16];
        float gxn = acc2[q] + bI[32 + n16];
        float rg = 1.0f / (1.0f + __expf(-(gxr + ghr)));
        float zg = 1.0f / (1.0f + __expf(-(gxz + ghz)));
        float ng = tanhf(gxn + rg * ghn);
        float hv = hmast[bi * 16 + n16];
        float hn2 = (1.0f - zg) * ng + zg * hv;
        hmast[bi * 16 + n16] = hn2;
        dst[(size_t)(batch0 + bi) * H_ + slice * 16 + n16] = f2b(hn2);
        if (lastStep)
          out_hn[(size_t)layer * SLAB + (size_t)(batch0 + bi) * H_ + slice * 16 + n16] = hn2;
      }
    }

    if (r < 256) {  // inter-round device barrier (per batch-half group, 96 WGs)
      __syncthreads();
      if (tid == 0) {
        __threadfence();  // release: drain + write back this WG's h stores (agent scope)
        __hip_atomic_fetch_add(&mycnt[r * CNT_STRIDE], 1, __ATOMIC_ACQ_REL,
                               __HIP_MEMORY_SCOPE_AGENT);
        int spins = 0;
        for (;;) {
          int c = ((spins & 15) == 15)
            ? __hip_atomic_load(&mycnt[r * CNT_STRIDE], __ATOMIC_ACQUIRE,
                                __HIP_MEMORY_SCOPE_AGENT)
            : __hip_atomic_load(&mycnt[r * CNT_STRIDE], __ATOMIC_RELAXED,
                                __HIP_MEMORY_SCOPE_AGENT);
          if (c >= NWG_GROUP) break;
          __builtin_amdgcn_s_sleep(1);
          if (++spins > (1 << 17)) break;  // hang guard; break => absmax fail, not timeout
        }
        __builtin_amdgcn_fence(__ATOMIC_ACQUIRE, "agent");  // one inv at exit, not per poll
      }
      __syncthreads();
    }
  }
}

// ---------------- regressor: pose = LeakyReLU(Y1 @ W1^T + b1) @ W2^T + b2 ----------------
__global__ __launch_bounds__(256) void regressor_kernel(
    const uint16_t* __restrict__ Y1, const uint16_t* __restrict__ W1b,
    const float* __restrict__ b1, const float* __restrict__ W2,
    const float* __restrict__ b2, float* __restrict__ pose)
{
  __shared__ float hdn[64 * 132];
  const int t = blockIdx.x;      // timestep
  const int tid = threadIdx.x;
  const int lane = tid & 63;
  const int wid = tid >> 6;
  const int n16 = lane & 15;
  const int kg = lane >> 4;

  const uint16_t* A  = Y1 + (size_t)(t + 1) * SLAB + (size_t)(wid * 16) * H_;
  const uint16_t* ap = A + (size_t)n16 * H_ + kg * 8;
  const uint16_t* bp = W1b + (size_t)n16 * H_ + kg * 8;

  f32x4 acc[8];
  #pragma unroll
  for (int i = 0; i < 8; ++i) acc[i] = (f32x4){0,0,0,0};

  for (int ks = 0; ks < 24; ++ks) {
    bf16x8 av = *reinterpret_cast<const bf16x8*>(ap + ks * 32);
    #pragma unroll
    for (int nt = 0; nt < 8; ++nt) {
      bf16x8 bv = *reinterpret_cast<const bf16x8*>(bp + (size_t)nt * 16 * H_ + ks * 32);
      acc[nt] = mfma16(av, bv, acc[nt]);
    }
  }
  #pragma unroll
  for (int nt = 0; nt < 8; ++nt) {
    #pragma unroll
    for (int q = 0; q < 4; ++q) {
      int brow = wid * 16 + 4 * kg + q;
      int col  = nt * 16 + n16;
      float v = acc[nt][q] + b1[col];
      v = (v >= 0.0f) ? v : 0.1f * v;   // LeakyReLU(0.1)
      hdn[brow * 132 + col] = v;
    }
  }
  __syncthreads();
  for (int idx = tid; idx < 384; idx += 256) {
    int b = idx / 6, o = idx % 6;
    const float* w2r = W2 + o * 128;
    const float* hr  = &hdn[b * 132];
    float s = b2[o];
    #pragma unroll 4
    for (int c = 0; c < 128; ++c) s += hr[c] * w2r[c];
    pose[(size_t)b * (SEQ * 6) + (size_t)t * 6 + o] = s;
  }
}

extern "C" void kernel_launch(void* const* d_in, const int* in_sizes, int n_in,
                              void* d_out, int out_size, void* d_ws, size_t ws_size,
                              hipStream_t stream) {
  const float* fv  = (const float*)d_in[0];
  const float* fi  = (const float*)d_in[1];
  // d_in[2] = ts (unused by the reference)
  const float* Wih = (const float*)d_in[3];
  const float* Whh = (const float*)d_in[4];
  const float* bih = (const float*)d_in[5];
  const float* bhh = (const float*)d_in[6];
  const float* W1  = (const float*)d_in[7];
  const float* b1  = (const float*)d_in[8];
  const float* W2  = (const float*)d_in[9];
  const float* b2  = (const float*)d_in[10];
  float* out = (float*)d_out;   // [pose: 64*256*6][h_n: 2*64*768]

  char* ws = (char*)d_ws;
  size_t off = 0;
  int* cnts = (int*)(ws + off);
  off += (size_t)2 * 257 * CNT_STRIDE * sizeof(int);
  off = (off + 255) & ~(size_t)255;
  uint16_t* Xbf = (uint16_t*)(ws + off); off += (size_t)SEQ * SLAB * 2;   // 25.2 MB
  uint16_t* Y0  = (uint16_t*)(ws + off); off += (size_t)257 * SLAB * 2;   // 25.3 MB
  uint16_t* Y1  = (uint16_t*)(ws + off); off += (size_t)257 * SLAB * 2;   // 25.3 MB
  uint16_t* W1b = (uint16_t*)(ws + off); off += (size_t)128 * H_ * 2;

  prep_kernel<<<2048, 256, 0, stream>>>(fv, fi, W1, Xbf, Y0, Y1, cnts, W1b);
  gru_persist<<<192, 256, 0, stream>>>(Wih, Whh, bih, bhh, Xbf, Y0, Y1, cnts, out + 98304);
  regressor_kernel<<<SEQ, 256, 0, stream>>>(Y1, W1b, b1, W2, b2, out);
}

// Round 6
// 6704.215 us; speedup vs baseline: 1.0058x; 1.0058x over previous
//
#include <hip/hip_runtime.h>
#include <stdint.h>

// PoseRNN: fused = cat(fv,fi) -> 2-layer GRU(768) -> Linear(768,128)+LeakyReLU(0.1) -> Linear(128,6)
// Persistent pipelined 2-layer GRU: 257 rounds, 192 WGs = 48 slices x 2 layers x 2 batch halves.
// Round-3: back to round-1's PROVEN coherence protocol (threadfence release + ACQ_REL arrive,
// acquire at exit), no inline asm anywhere. Changes vs round 1:
//   (a) spin polls are RELAXED (agent) with every-16th ACQUIRE + one acquire fence at exit
//       -> kills the per-poll buffer_inv storm that made each round 17.5us
//   (b) WROW 776->772 + B fragments via two ds_read_b64 -> 4 lanes/bank = wave64 b64 floor
//       (round 1: 8-way conflicts, 6.3e7 SQ_LDS_BANK_CONFLICT)
//   (c) all 24 A-fragments issued before the MFMA loop -> one miss-latency, not six serial

typedef __attribute__((ext_vector_type(8))) short bf16x8;   // 8 bf16 in 4 VGPRs
typedef __attribute__((ext_vector_type(4))) short bf16x4;   // 8B
typedef __attribute__((ext_vector_type(4))) float f32x4;

#define H_   768
#define TH3  2304
#define BATCH 64
#define SEQ  256
#define SLAB (BATCH * H_)   /* 49152 elems, one timestep of h/y for all batches */
#define WROW 772            /* padded LDS row stride (ushorts): start bank 2*n16+4*kg */
#define NWG_GROUP 96        /* WGs per barrier group (48 slices x 2 layers) */
#define CNT_STRIDE 32       /* ints per round-counter (128B line) */

__device__ __forceinline__ uint16_t f2b(float f) {
  union { float f; uint32_t u; } v; v.f = f;
  uint32_t u = v.u;
  return (uint16_t)((u + 0x7FFFu + ((u >> 16) & 1u)) >> 16);  // RNE
}

__device__ __forceinline__ f32x4 mfma16(bf16x8 a, bf16x8 b, f32x4 c) {
  return __builtin_amdgcn_mfma_f32_16x16x32_bf16(a, b, c, 0, 0, 0);
}

__device__ __forceinline__ bf16x8 ldB(const uint16_t* p) {   // two ds_read_b64 (8B-aligned rows)
  bf16x4 lo = *reinterpret_cast<const bf16x4*>(p);
  bf16x4 hi = *reinterpret_cast<const bf16x4*>(p + 4);
  bf16x8 r;
  r[0] = lo[0]; r[1] = lo[1]; r[2] = lo[2]; r[3] = lo[3];
  r[4] = hi[0]; r[5] = hi[1]; r[6] = hi[2]; r[7] = hi[3];
  return r;
}

// ---------------- prep: build time-major bf16 X, zero h0 slabs + counters, bf16 W1 -------------
__global__ __launch_bounds__(256) void prep_kernel(
    const float* __restrict__ fv, const float* __restrict__ fi,
    const float* __restrict__ W1,
    uint16_t* __restrict__ Xbf, uint16_t* __restrict__ Y0, uint16_t* __restrict__ Y1,
    int* __restrict__ cnts, uint16_t* __restrict__ W1b)
{
  const int NX = SEQ * SLAB;          // 12,582,912
  const int NY = SLAB;
  const int NC = 2 * 257 * CNT_STRIDE;
  const int NW = 128 * H_;
  const int total = NX + 2 * NY + NC + NW;
  for (int idx = blockIdx.x * blockDim.x + threadIdx.x; idx < total;
       idx += gridDim.x * blockDim.x) {
    if (idx < NX) {
      int s = idx / SLAB;
      int rem = idx - s * SLAB;
      int b = rem / H_;
      int h = rem - b * H_;
      float val = (h < 512) ? fv[((size_t)b * SEQ + s) * 512 + h]
                            : fi[((size_t)b * SEQ + s) * 256 + (h - 512)];
      Xbf[idx] = f2b(val);
    } else if (idx < NX + 2 * NY) {
      int k = idx - NX;
      if (k < NY) Y0[k] = 0; else Y1[k - NY] = 0;
    } else if (idx < NX + 2 * NY + NC) {
      cnts[idx - NX - 2 * NY] = 0;
    } else {
      int k = idx - NX - 2 * NY - NC;
      W1b[k] = f2b(W1[k]);
    }
  }
}

// ---------------- persistent pipelined 2-layer GRU ----------------
__global__ __launch_bounds__(256) void gru_persist(
    const float* __restrict__ Wih, const float* __restrict__ Whh,
    const float* __restrict__ bih, const float* __restrict__ bhh,
    const uint16_t* __restrict__ Xbf, uint16_t* __restrict__ Y0, uint16_t* __restrict__ Y1,
    int* __restrict__ cnts, float* __restrict__ out_hn)
{
  __shared__ __attribute__((aligned(16))) uint16_t Wx[48 * WROW];  // 74,112 B
  __shared__ __attribute__((aligned(16))) uint16_t Wh[48 * WROW];  // 74,112 B
  __shared__ float ghbuf[32 * 48];                                 //  6,144 B
  __shared__ float hmast[32 * 16];                                 //  2,048 B
  __shared__ float bI[48];
  __shared__ float bH[48];

  const int bid   = blockIdx.x;        // 0..191
  const int slice = bid % 48;          // hidden slice: units [slice*16, slice*16+16)
  const int layer = (bid / 48) & 1;    // 0 or 1
  const int bhalf = bid / 96;          // batch half (barrier group)
  const int tid  = threadIdx.x;
  const int lane = tid & 63;
  const int wid  = tid >> 6;           // 4 waves
  const int mblk = wid & 1;            // 16-batch sub-block within the 32-batch half
  const int isGh = wid >> 1;           // waves 0,1 -> x-GEMM (+combine); waves 2,3 -> h-GEMM
  const int n16  = lane & 15;
  const int kg   = lane >> 4;

  // --- one-time: weight slices -> LDS bf16; rows ordered [r(16) z(16) n(16)] ---
  const float* wx_g = Wih + (size_t)layer * TH3 * H_;
  const float* wh_g = Whh + (size_t)layer * TH3 * H_;
  for (int idx = tid; idx < 48 * H_; idx += 256) {
    int lr = idx / H_;
    int c  = idx - lr * H_;
    int gate = lr >> 4, j = lr & 15;
    size_t grow = (size_t)(gate * H_ + slice * 16 + j);
    Wx[lr * WROW + c] = f2b(wx_g[grow * H_ + c]);
    Wh[lr * WROW + c] = f2b(wh_g[grow * H_ + c]);
  }
  if (tid < 48) {
    int gate = tid >> 4, j = tid & 15;
    bI[tid] = bih[layer * TH3 + gate * H_ + slice * 16 + j];
    bH[tid] = bhh[layer * TH3 + gate * H_ + slice * 16 + j];
  }
  for (int idx = tid; idx < 32 * 16; idx += 256) hmast[idx] = 0.0f;
  __syncthreads();

  const int batch0 = bhalf * 32;
  int* mycnt = cnts + (size_t)bhalf * 257 * CNT_STRIDE;
  uint16_t* Yown = layer ? Y1 : Y0;

  for (int r = 0; r <= 256; ++r) {
    const bool active = (layer == 0) ? (r < 256) : (r >= 1);
    f32x4 acc0 = {0,0,0,0}, acc1 = {0,0,0,0}, acc2 = {0,0,0,0};
    uint16_t* dst = nullptr;

    if (active) {
      // layer0 step t=r:   x=Xbf[r],  h=Y0[r],   writes Y0[r+1]
      // layer1 step t=r-1: x=Y0[r],   h=Y1[r-1], writes Y1[r]
      const uint16_t* xs = (layer == 0) ? (Xbf + (size_t)r * SLAB) : (Y0 + (size_t)r * SLAB);
      const uint16_t* hs = (layer == 0) ? (Y0 + (size_t)r * SLAB) : (Y1 + (size_t)(r - 1) * SLAB);
      dst = Yown + (size_t)((layer == 0) ? (r + 1) : r) * SLAB;

      const uint16_t* A  = (isGh ? hs : xs) + (size_t)(batch0 + mblk * 16) * H_;
      const uint16_t* ap = A + (size_t)n16 * H_ + kg * 8;
      const uint16_t* Wl = isGh ? Wh : Wx;
      const uint16_t* bp = Wl + (size_t)n16 * WROW + kg * 8;

      // ---- A-operand: issue all 24 16B loads up front; one miss-latency instead of six ----
      bf16x8 afr[24];
      #pragma unroll
      for (int ks = 0; ks < 24; ++ks)
        afr[ks] = *reinterpret_cast<const bf16x8*>(ap + ks * 32);

      #pragma unroll 4
      for (int ks = 0; ks < 24; ++ks) {
        bf16x8 av  = afr[ks];
        bf16x8 bv0 = ldB(bp + ks * 32);
        bf16x8 bv1 = ldB(bp + 16 * WROW + ks * 32);
        bf16x8 bv2 = ldB(bp + 32 * WROW + ks * 32);
        acc0 = mfma16(av, bv0, acc0);
        acc1 = mfma16(av, bv1, acc1);
        acc2 = mfma16(av, bv2, acc2);
      }
      if (isGh) {
        #pragma unroll
        for (int q = 0; q < 4; ++q) {
          int bi = mblk * 16 + 4 * kg + q;          // D row = 4*(lane>>4)+q
          ghbuf[bi * 48 +      n16] = acc0[q];
          ghbuf[bi * 48 + 16 + n16] = acc1[q];
          ghbuf[bi * 48 + 32 + n16] = acc2[q];
        }
      }
    }
    __syncthreads();  // gh tiles visible to combine waves

    if (active && !isGh) {
      const bool lastStep = (layer == 0) ? (r == 255) : (r == 256);
      #pragma unroll
      for (int q = 0; q < 4; ++q) {
        int bi = mblk * 16 + 4 * kg + q;
        float ghr = ghbuf[bi * 48 +      n16] + bH[n16];
        float ghz = ghbuf[bi * 48 + 16 + n16] + bH[16 + n16];
        float ghn = ghbuf[bi * 48 + 32 + n16] + bH[32 + n16];
        float gxr = acc0[q] + bI[n16];
        float gxz = acc1[q] + bI[16 + n16];
        float gxn = acc2[q] + bI[32 + n16];
        float rg = 1.0f / (1.0f + __expf(-(gxr + ghr)));
        float zg = 1.0f / (1.0f + __expf(-(gxz + ghz)));
        float ng = tanhf(gxn + rg * ghn);
        float hv = hmast[bi * 16 + n16];
        float hn2 = (1.0f - zg) * ng + zg * hv;
        hmast[bi * 16 + n16] = hn2;
        dst[(size_t)(batch0 + bi) * H_ + slice * 16 + n16] = f2b(hn2);
        if (lastStep)
          out_hn[(size_t)layer * SLAB + (size_t)(batch0 + bi) * H_ + slice * 16 + n16] = hn2;
      }
    }

    if (r < 256) {  // inter-round device barrier (per batch-half group, 96 WGs)
      __syncthreads();
      if (tid == 0) {
        __threadfence();  // release: drain + write back this WG's h stores (agent scope)
        __hip_atomic_fetch_add(&mycnt[r * CNT_STRIDE], 1, __ATOMIC_ACQ_REL,
                               __HIP_MEMORY_SCOPE_AGENT);
        int spins = 0;
        for (;;) {
          int c = ((spins & 15) == 15)
            ? __hip_atomic_load(&mycnt[r * CNT_STRIDE], __ATOMIC_ACQUIRE,
                                __HIP_MEMORY_SCOPE_AGENT)
            : __hip_atomic_load(&mycnt[r * CNT_STRIDE], __ATOMIC_RELAXED,
                                __HIP_MEMORY_SCOPE_AGENT);
          if (c >= NWG_GROUP) break;
          __builtin_amdgcn_s_sleep(1);
          if (++spins > (1 << 17)) break;  // hang guard; break => absmax fail, not timeout
        }
        __builtin_amdgcn_fence(__ATOMIC_ACQUIRE, "agent");  // one inv at exit, not per poll
      }
      __syncthreads();
    }
  }
}

// ---------------- regressor: pose = LeakyReLU(Y1 @ W1^T + b1) @ W2^T + b2 ----------------
__global__ __launch_bounds__(256) void regressor_kernel(
    const uint16_t* __restrict__ Y1, const uint16_t* __restrict__ W1b,
    const float* __restrict__ b1, const float* __restrict__ W2,
    const float* __restrict__ b2, float* __restrict__ pose)
{
  __shared__ float hdn[64 * 132];
  const int t = blockIdx.x;      // timestep
  const int tid = threadIdx.x;
  const int lane = tid & 63;
  const int wid = tid >> 6;
  const int n16 = lane & 15;
  const int kg = lane >> 4;

  const uint16_t* A  = Y1 + (size_t)(t + 1) * SLAB + (size_t)(wid * 16) * H_;
  const uint16_t* ap = A + (size_t)n16 * H_ + kg * 8;
  const uint16_t* bp = W1b + (size_t)n16 * H_ + kg * 8;

  f32x4 acc[8];
  #pragma unroll
  for (int i = 0; i < 8; ++i) acc[i] = (f32x4){0,0,0,0};

  for (int ks = 0; ks < 24; ++ks) {
    bf16x8 av = *reinterpret_cast<const bf16x8*>(ap + ks * 32);
    #pragma unroll
    for (int nt = 0; nt < 8; ++nt) {
      bf16x8 bv = *reinterpret_cast<const bf16x8*>(bp + (size_t)nt * 16 * H_ + ks * 32);
      acc[nt] = mfma16(av, bv, acc[nt]);
    }
  }
  #pragma unroll
  for (int nt = 0; nt < 8; ++nt) {
    #pragma unroll
    for (int q = 0; q < 4; ++q) {
      int brow = wid * 16 + 4 * kg + q;
      int col  = nt * 16 + n16;
      float v = acc[nt][q] + b1[col];
      v = (v >= 0.0f) ? v : 0.1f * v;   // LeakyReLU(0.1)
      hdn[brow * 132 + col] = v;
    }
  }
  __syncthreads();
  for (int idx = tid; idx < 384; idx += 256) {
    int b = idx / 6, o = idx % 6;
    const float* w2r = W2 + o * 128;
    const float* hr  = &hdn[b * 132];
    float s = b2[o];
    #pragma unroll 4
    for (int c = 0; c < 128; ++c) s += hr[c] * w2r[c];
    pose[(size_t)b * (SEQ * 6) + (size_t)t * 6 + o] = s;
  }
}

extern "C" void kernel_launch(void* const* d_in, const int* in_sizes, int n_in,
                              void* d_out, int out_size, void* d_ws, size_t ws_size,
                              hipStream_t stream) {
  const float* fv  = (const float*)d_in[0];
  const float* fi  = (const float*)d_in[1];
  // d_in[2] = ts (unused by the reference)
  const float* Wih = (const float*)d_in[3];
  const float* Whh = (const float*)d_in[4];
  const float* bih = (const float*)d_in[5];
  const float* bhh = (const float*)d_in[6];
  const float* W1  = (const float*)d_in[7];
  const float* b1  = (const float*)d_in[8];
  const float* W2  = (const float*)d_in[9];
  const float* b2  = (const float*)d_in[10];
  float* out = (float*)d_out;   // [pose: 64*256*6][h_n: 2*64*768]

  char* ws = (char*)d_ws;
  size_t off = 0;
  int* cnts = (int*)(ws + off);
  off += (size_t)2 * 257 * CNT_STRIDE * sizeof(int);
  off = (off + 255) & ~(size_t)255;
  uint16_t* Xbf = (uint16_t*)(ws + off); off += (size_t)SEQ * SLAB * 2;   // 25.2 MB
  uint16_t* Y0  = (uint16_t*)(ws + off); off += (size_t)257 * SLAB * 2;   // 25.3 MB
  uint16_t* Y1  = (uint16_t*)(ws + off); off += (size_t)257 * SLAB * 2;   // 25.3 MB
  uint16_t* W1b = (uint16_t*)(ws + off); off += (size_t)128 * H_ * 2;

  prep_kernel<<<2048, 256, 0, stream>>>(fv, fi, W1, Xbf, Y0, Y1, cnts, W1b);
  gru_persist<<<192, 256, 0, stream>>>(Wih, Whh, bih, bhh, Xbf, Y0, Y1, cnts, out + 98304);
  regressor_kernel<<<SEQ, 256, 0, stream>>>(Y1, W1b, b1, W2, b2, out);
}

// Round 7
// 3765.917 us; speedup vs baseline: 1.7906x; 1.7802x over previous
//
#include <hip/hip_runtime.h>
#include <stdint.h>

// PoseRNN: fused = cat(fv,fi) -> 2-layer GRU(768) -> Linear(768,128)+LeakyReLU(0.1) -> Linear(128,6)
// Persistent pipelined 2-layer GRU: 257 rounds, 192 WGs = 48 slices x 2 layers x 2 batch halves.
// Round-7: FENCELESS inter-WG protocol. Round 6 proved fence-based agent coherence costs
// ~20us/round (threadfence -> buffer_wbl2 flushed whole dirty L2 per WG per round: WRITE_SIZE
// 4.77GB). Round 1's acquire-spin variant paid the same via buffer_inv (FETCH 310MB).
// New protocol (zero wbl2/inv in the loop):
//   - h-slab stores: RELAXED AGENT atomic dword stores (write-through to coherent L3,
//     nothing dirty in L2), packed in pairs via __shfl_xor. Drained by s_waitcnt +
//     __syncthreads (vmcnt(0)) before the barrier arrive.
//   - barrier: relaxed agent fetch_add + relaxed agent spin loads. No fences at all.
//   - h/x slab loads: PLAIN cached loads. Correct because every slab line is write-once and
//     never cached by any reader before its round's barrier (first touch fetches from L3,
//     which write-through already populated). L2 stays warm for Xbf/weights forever.

typedef __attribute__((ext_vector_type(8))) short bf16x8;   // 8 bf16 in 4 VGPRs
typedef __attribute__((ext_vector_type(4))) short bf16x4;   // 8B
typedef __attribute__((ext_vector_type(4))) float f32x4;

#define H_   768
#define TH3  2304
#define BATCH 64
#define SEQ  256
#define SLAB (BATCH * H_)   /* 49152 elems, one timestep of h/y for all batches */
#define WROW 772            /* padded LDS row stride (ushorts): start bank 2*n16+4*kg */
#define NWG_GROUP 96        /* WGs per barrier group (48 slices x 2 layers) */
#define CNT_STRIDE 32       /* ints per round-counter (128B line) */

__device__ __forceinline__ uint16_t f2b(float f) {
  union { float f; uint32_t u; } v; v.f = f;
  uint32_t u = v.u;
  return (uint16_t)((u + 0x7FFFu + ((u >> 16) & 1u)) >> 16);  // RNE
}

__device__ __forceinline__ f32x4 mfma16(bf16x8 a, bf16x8 b, f32x4 c) {
  return __builtin_amdgcn_mfma_f32_16x16x32_bf16(a, b, c, 0, 0, 0);
}

__device__ __forceinline__ bf16x8 ldB(const uint16_t* p) {   // two ds_read_b64 (8B-aligned rows)
  bf16x4 lo = *reinterpret_cast<const bf16x4*>(p);
  bf16x4 hi = *reinterpret_cast<const bf16x4*>(p + 4);
  bf16x8 r;
  r[0] = lo[0]; r[1] = lo[1]; r[2] = lo[2]; r[3] = lo[3];
  r[4] = hi[0]; r[5] = hi[1]; r[6] = hi[2]; r[7] = hi[3];
  return r;
}

// ---------------- prep: build time-major bf16 X, zero h0 slabs + counters, bf16 W1 -------------
__global__ __launch_bounds__(256) void prep_kernel(
    const float* __restrict__ fv, const float* __restrict__ fi,
    const float* __restrict__ W1,
    uint16_t* __restrict__ Xbf, uint16_t* __restrict__ Y0, uint16_t* __restrict__ Y1,
    int* __restrict__ cnts, uint16_t* __restrict__ W1b)
{
  const int NX = SEQ * SLAB;          // 12,582,912
  const int NY = SLAB;
  const int NC = 2 * 257 * CNT_STRIDE;
  const int NW = 128 * H_;
  const int total = NX + 2 * NY + NC + NW;
  for (int idx = blockIdx.x * blockDim.x + threadIdx.x; idx < total;
       idx += gridDim.x * blockDim.x) {
    if (idx < NX) {
      int s = idx / SLAB;
      int rem = idx - s * SLAB;
      int b = rem / H_;
      int h = rem - b * H_;
      float val = (h < 512) ? fv[((size_t)b * SEQ + s) * 512 + h]
                            : fi[((size_t)b * SEQ + s) * 256 + (h - 512)];
      Xbf[idx] = f2b(val);
    } else if (idx < NX + 2 * NY) {
      int k = idx - NX;
      if (k < NY) Y0[k] = 0; else Y1[k - NY] = 0;
    } else if (idx < NX + 2 * NY + NC) {
      cnts[idx - NX - 2 * NY] = 0;
    } else {
      int k = idx - NX - 2 * NY - NC;
      W1b[k] = f2b(W1[k]);
    }
  }
}

// ---------------- persistent pipelined 2-layer GRU ----------------
__global__ __launch_bounds__(256) void gru_persist(
    const float* __restrict__ Wih, const float* __restrict__ Whh,
    const float* __restrict__ bih, const float* __restrict__ bhh,
    const uint16_t* __restrict__ Xbf, uint16_t* __restrict__ Y0, uint16_t* __restrict__ Y1,
    int* __restrict__ cnts, float* __restrict__ out_hn)
{
  __shared__ __attribute__((aligned(16))) uint16_t Wx[48 * WROW];  // 74,112 B
  __shared__ __attribute__((aligned(16))) uint16_t Wh[48 * WROW];  // 74,112 B
  __shared__ float ghbuf[32 * 48];                                 //  6,144 B
  __shared__ float hmast[32 * 16];                                 //  2,048 B
  __shared__ float bI[48];
  __shared__ float bH[48];

  const int bid   = blockIdx.x;        // 0..191
  const int slice = bid % 48;          // hidden slice: units [slice*16, slice*16+16)
  const int layer = (bid / 48) & 1;    // 0 or 1
  const int bhalf = bid / 96;          // batch half (barrier group)
  const int tid  = threadIdx.x;
  const int lane = tid & 63;
  const int wid  = tid >> 6;           // 4 waves
  const int mblk = wid & 1;            // 16-batch sub-block within the 32-batch half
  const int isGh = wid >> 1;           // waves 0,1 -> x-GEMM (+combine); waves 2,3 -> h-GEMM
  const int n16  = lane & 15;
  const int kg   = lane >> 4;

  // --- one-time: weight slices -> LDS bf16; rows ordered [r(16) z(16) n(16)] ---
  const float* wx_g = Wih + (size_t)layer * TH3 * H_;
  const float* wh_g = Whh + (size_t)layer * TH3 * H_;
  for (int idx = tid; idx < 48 * H_; idx += 256) {
    int lr = idx / H_;
    int c  = idx - lr * H_;
    int gate = lr >> 4, j = lr & 15;
    size_t grow = (size_t)(gate * H_ + slice * 16 + j);
    Wx[lr * WROW + c] = f2b(wx_g[grow * H_ + c]);
    Wh[lr * WROW + c] = f2b(wh_g[grow * H_ + c]);
  }
  if (tid < 48) {
    int gate = tid >> 4, j = tid & 15;
    bI[tid] = bih[layer * TH3 + gate * H_ + slice * 16 + j];
    bH[tid] = bhh[layer * TH3 + gate * H_ + slice * 16 + j];
  }
  for (int idx = tid; idx < 32 * 16; idx += 256) hmast[idx] = 0.0f;
  __syncthreads();

  const int batch0 = bhalf * 32;
  int* mycnt = cnts + (size_t)bhalf * 257 * CNT_STRIDE;
  uint16_t* Yown = layer ? Y1 : Y0;

  for (int r = 0; r <= 256; ++r) {
    const bool active = (layer == 0) ? (r < 256) : (r >= 1);
    f32x4 acc0 = {0,0,0,0}, acc1 = {0,0,0,0}, acc2 = {0,0,0,0};
    uint16_t* dst = nullptr;

    if (active) {
      // layer0 step t=r:   x=Xbf[r],  h=Y0[r],   writes Y0[r+1]
      // layer1 step t=r-1: x=Y0[r],   h=Y1[r-1], writes Y1[r]
      const uint16_t* xs = (layer == 0) ? (Xbf + (size_t)r * SLAB) : (Y0 + (size_t)r * SLAB);
      const uint16_t* hs = (layer == 0) ? (Y0 + (size_t)r * SLAB) : (Y1 + (size_t)(r - 1) * SLAB);
      dst = Yown + (size_t)((layer == 0) ? (r + 1) : r) * SLAB;

      const uint16_t* A  = (isGh ? hs : xs) + (size_t)(batch0 + mblk * 16) * H_;
      const uint16_t* ap = A + (size_t)n16 * H_ + kg * 8;
      const uint16_t* Wl = isGh ? Wh : Wx;
      const uint16_t* bp = Wl + (size_t)n16 * WROW + kg * 8;

      // ---- A-operand: issue all 24 16B loads up front; one miss-latency instead of six ----
      bf16x8 afr[24];
      #pragma unroll
      for (int ks = 0; ks < 24; ++ks)
        afr[ks] = *reinterpret_cast<const bf16x8*>(ap + ks * 32);

      #pragma unroll 4
      for (int ks = 0; ks < 24; ++ks) {
        bf16x8 av  = afr[ks];
        bf16x8 bv0 = ldB(bp + ks * 32);
        bf16x8 bv1 = ldB(bp + 16 * WROW + ks * 32);
        bf16x8 bv2 = ldB(bp + 32 * WROW + ks * 32);
        acc0 = mfma16(av, bv0, acc0);
        acc1 = mfma16(av, bv1, acc1);
        acc2 = mfma16(av, bv2, acc2);
      }
      if (isGh) {
        #pragma unroll
        for (int q = 0; q < 4; ++q) {
          int bi = mblk * 16 + 4 * kg + q;          // D row = 4*(lane>>4)+q
          ghbuf[bi * 48 +      n16] = acc0[q];
          ghbuf[bi * 48 + 16 + n16] = acc1[q];
          ghbuf[bi * 48 + 32 + n16] = acc2[q];
        }
      }
    }
    __syncthreads();  // gh tiles visible to combine waves

    if (active && !isGh) {
      const bool lastStep = (layer == 0) ? (r == 255) : (r == 256);
      #pragma unroll
      for (int q = 0; q < 4; ++q) {
        int bi = mblk * 16 + 4 * kg + q;
        float ghr = ghbuf[bi * 48 +      n16] + bH[n16];
        float ghz = ghbuf[bi * 48 + 16 + n16] + bH[16 + n16];
        float ghn = ghbuf[bi * 48 + 32 + n16] + bH[32 + n16];
        float gxr = acc0[q] + bI[n16];
        float gxz = acc1[q] + bI[16 + n16];
        float gxn = acc2[q] + bI[32 + n16];
        float rg = 1.0f / (1.0f + __expf(-(gxr + ghr)));
        float zg = 1.0f / (1.0f + __expf(-(gxz + ghz)));
        float ng = tanhf(gxn + rg * ghn);
        float hv = hmast[bi * 16 + n16];
        float hn2 = (1.0f - zg) * ng + zg * hv;
        hmast[bi * 16 + n16] = hn2;
        // ---- write-through (agent, relaxed) packed dword store: no dirty L2, no fences ----
        uint32_t lo = (uint32_t)f2b(hn2);
        uint32_t partner = (uint32_t)__shfl_xor((int)lo, 1, 64);  // col n16^1's bf16 bits
        if ((n16 & 1) == 0) {
          uint32_t pack = lo | (partner << 16);   // little-endian: col n16 low, n16+1 high
          uint32_t* p = (uint32_t*)(dst + (size_t)(batch0 + bi) * H_ + slice * 16 + n16);
          __hip_atomic_store(p, pack, __ATOMIC_RELAXED, __HIP_MEMORY_SCOPE_AGENT);
        }
        if (lastStep)
          out_hn[(size_t)layer * SLAB + (size_t)(batch0 + bi) * H_ + slice * 16 + n16] = hn2;
      }
      __builtin_amdgcn_s_waitcnt(0);  // stores ACKed at coherence point before arrive
    }

    if (r < 256) {  // inter-round device barrier (per batch-half group, 96 WGs), fenceless
      __syncthreads();   // also drains vmcnt(0) for all waves
      if (tid == 0) {
        __hip_atomic_fetch_add(&mycnt[r * CNT_STRIDE], 1, __ATOMIC_RELAXED,
                               __HIP_MEMORY_SCOPE_AGENT);
        int spins = 0;
        while (__hip_atomic_load(&mycnt[r * CNT_STRIDE], __ATOMIC_RELAXED,
                                 __HIP_MEMORY_SCOPE_AGENT) < NWG_GROUP) {
          __builtin_amdgcn_s_sleep(1);
          if (++spins > (1 << 16)) break;  // hang guard; break => absmax fail, not timeout
        }
      }
      __syncthreads();
    }
  }
}

// ---------------- regressor: pose = LeakyReLU(Y1 @ W1^T + b1) @ W2^T + b2 ----------------
__global__ __launch_bounds__(256) void regressor_kernel(
    const uint16_t* __restrict__ Y1, const uint16_t* __restrict__ W1b,
    const float* __restrict__ b1, const float* __restrict__ W2,
    const float* __restrict__ b2, float* __restrict__ pose)
{
  __shared__ float hdn[64 * 132];
  const int t = blockIdx.x;      // timestep
  const int tid = threadIdx.x;
  const int lane = tid & 63;
  const int wid = tid >> 6;
  const int n16 = lane & 15;
  const int kg = lane >> 4;

  const uint16_t* A  = Y1 + (size_t)(t + 1) * SLAB + (size_t)(wid * 16) * H_;
  const uint16_t* ap = A + (size_t)n16 * H_ + kg * 8;
  const uint16_t* bp = W1b + (size_t)n16 * H_ + kg * 8;

  f32x4 acc[8];
  #pragma unroll
  for (int i = 0; i < 8; ++i) acc[i] = (f32x4){0,0,0,0};

  for (int ks = 0; ks < 24; ++ks) {
    bf16x8 av = *reinterpret_cast<const bf16x8*>(ap + ks * 32);
    #pragma unroll
    for (int nt = 0; nt < 8; ++nt) {
      bf16x8 bv = *reinterpret_cast<const bf16x8*>(bp + (size_t)nt * 16 * H_ + ks * 32);
      acc[nt] = mfma16(av, bv, acc[nt]);
    }
  }
  #pragma unroll
  for (int nt = 0; nt < 8; ++nt) {
    #pragma unroll
    for (int q = 0; q < 4; ++q) {
      int brow = wid * 16 + 4 * kg + q;
      int col  = nt * 16 + n16;
      float v = acc[nt][q] + b1[col];
      v = (v >= 0.0f) ? v : 0.1f * v;   // LeakyReLU(0.1)
      hdn[brow * 132 + col] = v;
    }
  }
  __syncthreads();
  for (int idx = tid; idx < 384; idx += 256) {
    int b = idx / 6, o = idx % 6;
    const float* w2r = W2 + o * 128;
    const float* hr  = &hdn[b * 132];
    float s = b2[o];
    #pragma unroll 4
    for (int c = 0; c < 128; ++c) s += hr[c] * w2r[c];
    pose[(size_t)b * (SEQ * 6) + (size_t)t * 6 + o] = s;
  }
}

extern "C" void kernel_launch(void* const* d_in, const int* in_sizes, int n_in,
                              void* d_out, int out_size, void* d_ws, size_t ws_size,
                              hipStream_t stream) {
  const float* fv  = (const float*)d_in[0];
  const float* fi  = (const float*)d_in[1];
  // d_in[2] = ts (unused by the reference)
  const float* Wih = (const float*)d_in[3];
  const float* Whh = (const float*)d_in[4];
  const float* bih = (const float*)d_in[5];
  const float* bhh = (const float*)d_in[6];
  const float* W1  = (const float*)d_in[7];
  const float* b1  = (const float*)d_in[8];
  const float* W2  = (const float*)d_in[9];
  const float* b2  = (const float*)d_in[10];
  float* out = (float*)d_out;   // [pose: 64*256*6][h_n: 2*64*768]

  char* ws = (char*)d_ws;
  size_t off = 0;
  int* cnts = (int*)(ws + off);
  off += (size_t)2 * 257 * CNT_STRIDE * sizeof(int);
  off = (off + 255) & ~(size_t)255;
  uint16_t* Xbf = (uint16_t*)(ws + off); off += (size_t)SEQ * SLAB * 2;   // 25.2 MB
  uint16_t* Y0  = (uint16_t*)(ws + off); off += (size_t)257 * SLAB * 2;   // 25.3 MB
  uint16_t* Y1  = (uint16_t*)(ws + off); off += (size_t)257 * SLAB * 2;   // 25.3 MB
  uint16_t* W1b = (uint16_t*)(ws + off); off += (size_t)128 * H_ * 2;

  prep_kernel<<<2048, 256, 0, stream>>>(fv, fi, W1, Xbf, Y0, Y1, cnts, W1b);
  gru_persist<<<192, 256, 0, stream>>>(Wih, Whh, bih, bhh, Xbf, Y0, Y1, cnts, out + 98304);
  regressor_kernel<<<SEQ, 256, 0, stream>>>(Y1, W1b, b1, W2, b2, out);
}

// Round 8
// 3122.116 us; speedup vs baseline: 2.1598x; 1.2062x over previous
//
#include <hip/hip_runtime.h>
#include <stdint.h>

// PoseRNN: fused = cat(fv,fi) -> 2-layer GRU(768) -> Linear(768,128)+LeakyReLU(0.1) -> Linear(128,6)
// Persistent pipelined 2-layer GRU: 257 rounds, 192 WGs = 48 slices x 2 layers x 2 batch halves.
// Round-8: FLAG-VECTOR dependency tracking instead of a counting barrier.
// Evidence: rounds 1/6/7 all cost ~15-17us/round despite three different visibility protocols;
// the only shared structure was 96 serialized fetch_adds to ONE address per round (~150ns each
// at the coherence point = ~14us convoy). Replaced by:
//   - each WG stores its own flag  flags[r][bid]=1  (relaxed agent dword store, parallel)
//   - each WAVE polls exactly the 48 flags it depends on (one vector far-load per iteration)
//   - layer0 x-waves have no dependency at all and run ahead of the poll
// Visibility protocol unchanged from round 7 (proven): write-through relaxed-agent h stores,
// s_waitcnt + syncthreads drain, relaxed-agent polls (L2-bypassing), zero fences in the loop.

typedef __attribute__((ext_vector_type(8))) short bf16x8;   // 8 bf16 in 4 VGPRs
typedef __attribute__((ext_vector_type(4))) short bf16x4;   // 8B
typedef __attribute__((ext_vector_type(4))) float f32x4;

#define H_   768
#define TH3  2304
#define BATCH 64
#define SEQ  256
#define SLAB (BATCH * H_)   /* 49152 elems, one timestep of h/y for all batches */
#define WROW 772            /* padded LDS row stride (ushorts): start bank 2*n16+4*kg */
#define FL_STRIDE 256       /* ints per round in the flag array (192 used, 1KB-aligned) */

__device__ __forceinline__ uint16_t f2b(float f) {
  union { float f; uint32_t u; } v; v.f = f;
  uint32_t u = v.u;
  return (uint16_t)((u + 0x7FFFu + ((u >> 16) & 1u)) >> 16);  // RNE
}

__device__ __forceinline__ f32x4 mfma16(bf16x8 a, bf16x8 b, f32x4 c) {
  return __builtin_amdgcn_mfma_f32_16x16x32_bf16(a, b, c, 0, 0, 0);
}

__device__ __forceinline__ bf16x8 ldB(const uint16_t* p) {   // two ds_read_b64 (8B-aligned rows)
  bf16x4 lo = *reinterpret_cast<const bf16x4*>(p);
  bf16x4 hi = *reinterpret_cast<const bf16x4*>(p + 4);
  bf16x8 r;
  r[0] = lo[0]; r[1] = lo[1]; r[2] = lo[2]; r[3] = lo[3];
  r[4] = hi[0]; r[5] = hi[1]; r[6] = hi[2]; r[7] = hi[3];
  return r;
}

// ---------------- prep: build time-major bf16 X, zero h0 slabs + flags, bf16 W1 -------------
__global__ __launch_bounds__(256) void prep_kernel(
    const float* __restrict__ fv, const float* __restrict__ fi,
    const float* __restrict__ W1,
    uint16_t* __restrict__ Xbf, uint16_t* __restrict__ Y0, uint16_t* __restrict__ Y1,
    int* __restrict__ flags, uint16_t* __restrict__ W1b)
{
  const int NX = SEQ * SLAB;          // 12,582,912
  const int NY = SLAB;
  const int NC = 257 * FL_STRIDE;     // 65,792 flag ints
  const int NW = 128 * H_;
  const int total = NX + 2 * NY + NC + NW;
  for (int idx = blockIdx.x * blockDim.x + threadIdx.x; idx < total;
       idx += gridDim.x * blockDim.x) {
    if (idx < NX) {
      int s = idx / SLAB;
      int rem = idx - s * SLAB;
      int b = rem / H_;
      int h = rem - b * H_;
      float val = (h < 512) ? fv[((size_t)b * SEQ + s) * 512 + h]
                            : fi[((size_t)b * SEQ + s) * 256 + (h - 512)];
      Xbf[idx] = f2b(val);
    } else if (idx < NX + 2 * NY) {
      int k = idx - NX;
      if (k < NY) Y0[k] = 0; else Y1[k - NY] = 0;
    } else if (idx < NX + 2 * NY + NC) {
      flags[idx - NX - 2 * NY] = 0;
    } else {
      int k = idx - NX - 2 * NY - NC;
      W1b[k] = f2b(W1[k]);
    }
  }
}

// ---------------- persistent pipelined 2-layer GRU ----------------
__global__ __launch_bounds__(256) void gru_persist(
    const float* __restrict__ Wih, const float* __restrict__ Whh,
    const float* __restrict__ bih, const float* __restrict__ bhh,
    const uint16_t* __restrict__ Xbf, uint16_t* __restrict__ Y0, uint16_t* __restrict__ Y1,
    int* __restrict__ flags, float* __restrict__ out_hn)
{
  __shared__ __attribute__((aligned(16))) uint16_t Wx[48 * WROW];  // 74,112 B
  __shared__ __attribute__((aligned(16))) uint16_t Wh[48 * WROW];  // 74,112 B
  __shared__ float ghbuf[32 * 48];                                 //  6,144 B
  __shared__ float hmast[32 * 16];                                 //  2,048 B
  __shared__ float bI[48];
  __shared__ float bH[48];

  const int bid   = blockIdx.x;        // 0..191
  const int slice = bid % 48;          // hidden slice: units [slice*16, slice*16+16)
  const int layer = (bid / 48) & 1;    // 0 or 1
  const int bhalf = bid / 96;          // batch half
  const int tid  = threadIdx.x;
  const int lane = tid & 63;
  const int wid  = tid >> 6;           // 4 waves
  const int mblk = wid & 1;            // 16-batch sub-block within the 32-batch half
  const int isGh = wid >> 1;           // waves 0,1 -> x-GEMM (+combine); waves 2,3 -> h-GEMM
  const int n16  = lane & 15;
  const int kg   = lane >> 4;

  // --- one-time: weight slices -> LDS bf16; rows ordered [r(16) z(16) n(16)] ---
  const float* wx_g = Wih + (size_t)layer * TH3 * H_;
  const float* wh_g = Whh + (size_t)layer * TH3 * H_;
  for (int idx = tid; idx < 48 * H_; idx += 256) {
    int lr = idx / H_;
    int c  = idx - lr * H_;
    int gate = lr >> 4, j = lr & 15;
    size_t grow = (size_t)(gate * H_ + slice * 16 + j);
    Wx[lr * WROW + c] = f2b(wx_g[grow * H_ + c]);
    Wh[lr * WROW + c] = f2b(wh_g[grow * H_ + c]);
  }
  if (tid < 48) {
    int gate = tid >> 4, j = tid & 15;
    bI[tid] = bih[layer * TH3 + gate * H_ + slice * 16 + j];
    bH[tid] = bhh[layer * TH3 + gate * H_ + slice * 16 + j];
  }
  for (int idx = tid; idx < 32 * 16; idx += 256) hmast[idx] = 0.0f;
  __syncthreads();

  const int batch0 = bhalf * 32;
  uint16_t* Yown = layer ? Y1 : Y0;

  for (int r = 0; r <= 256; ++r) {
    const bool active = (layer == 0) ? (r < 256) : (r >= 1);
    f32x4 acc0 = {0,0,0,0}, acc1 = {0,0,0,0}, acc2 = {0,0,0,0};
    uint16_t* dst = nullptr;

    if (active) {
      // layer0 step t=r:   x=Xbf[r],  h=Y0[r],   writes Y0[r+1]
      // layer1 step t=r-1: x=Y0[r],   h=Y1[r-1], writes Y1[r]
      const uint16_t* xs = (layer == 0) ? (Xbf + (size_t)r * SLAB) : (Y0 + (size_t)r * SLAB);
      const uint16_t* hs = (layer == 0) ? (Y0 + (size_t)r * SLAB) : (Y1 + (size_t)(r - 1) * SLAB);
      dst = Yown + (size_t)((layer == 0) ? (r + 1) : r) * SLAB;

      // ---- per-wave dependency poll (write-once flags; relaxed agent loads bypass L2) ----
      // gh waves need own (layer,bhalf) group's round-(r-1) flags (h slab producers).
      // x  waves of layer1 need layer0 group's round-(r-1) flags (Y0[r] producers).
      // x  waves of layer0 need nothing: Xbf is static -> run ahead of the poll.
      const int* fb = nullptr;
      if (r >= 1) {
        if (isGh)            fb = flags + (size_t)(r - 1) * FL_STRIDE + bhalf * 96 + layer * 48;
        else if (layer == 1) fb = flags + (size_t)(r - 1) * FL_STRIDE + bhalf * 96;
      }
      if (fb) {
        const int* fp = fb + (lane < 48 ? lane : 0);
        int spins = 0;
        for (;;) {
          int v = __hip_atomic_load(fp, __ATOMIC_RELAXED, __HIP_MEMORY_SCOPE_AGENT);
          if (lane >= 48) v = 1;
          if (__all(v != 0)) break;
          if (++spins > (1 << 15)) break;  // hang guard; break => absmax fail, not timeout
          __builtin_amdgcn_s_sleep(1);
        }
      }

      const uint16_t* A  = (isGh ? hs : xs) + (size_t)(batch0 + mblk * 16) * H_;
      const uint16_t* ap = A + (size_t)n16 * H_ + kg * 8;
      const uint16_t* Wl = isGh ? Wh : Wx;
      const uint16_t* bp = Wl + (size_t)n16 * WROW + kg * 8;

      // ---- A-operand: issue all 24 16B loads up front; one miss-latency instead of six ----
      bf16x8 afr[24];
      #pragma unroll
      for (int ks = 0; ks < 24; ++ks)
        afr[ks] = *reinterpret_cast<const bf16x8*>(ap + ks * 32);

      #pragma unroll 4
      for (int ks = 0; ks < 24; ++ks) {
        bf16x8 av  = afr[ks];
        bf16x8 bv0 = ldB(bp + ks * 32);
        bf16x8 bv1 = ldB(bp + 16 * WROW + ks * 32);
        bf16x8 bv2 = ldB(bp + 32 * WROW + ks * 32);
        acc0 = mfma16(av, bv0, acc0);
        acc1 = mfma16(av, bv1, acc1);
        acc2 = mfma16(av, bv2, acc2);
      }
      if (isGh) {
        #pragma unroll
        for (int q = 0; q < 4; ++q) {
          int bi = mblk * 16 + 4 * kg + q;          // D row = 4*(lane>>4)+q
          ghbuf[bi * 48 +      n16] = acc0[q];
          ghbuf[bi * 48 + 16 + n16] = acc1[q];
          ghbuf[bi * 48 + 32 + n16] = acc2[q];
        }
      }
    }
    __syncthreads();  // sync #1: gh tiles visible to combine waves

    if (active && !isGh) {
      const bool lastStep = (layer == 0) ? (r == 255) : (r == 256);
      #pragma unroll
      for (int q = 0; q < 4; ++q) {
        int bi = mblk * 16 + 4 * kg + q;
        float ghr = ghbuf[bi * 48 +      n16] + bH[n16];
        float ghz = ghbuf[bi * 48 + 16 + n16] + bH[16 + n16];
        float ghn = ghbuf[bi * 48 + 32 + n16] + bH[32 + n16];
        float gxr = acc0[q] + bI[n16];
        float gxz = acc1[q] + bI[16 + n16];
        float gxn = acc2[q] + bI[32 + n16];
        float rg = 1.0f / (1.0f + __expf(-(gxr + ghr)));
        float zg = 1.0f / (1.0f + __expf(-(gxz + ghz)));
        float ng = tanhf(gxn + rg * ghn);
        float hv = hmast[bi * 16 + n16];
        float hn2 = (1.0f - zg) * ng + zg * hv;
        hmast[bi * 16 + n16] = hn2;
        // ---- write-through (agent, relaxed) packed dword store: no dirty L2, no fences ----
        uint32_t lo = (uint32_t)f2b(hn2);
        uint32_t partner = (uint32_t)__shfl_xor((int)lo, 1, 64);  // col n16^1's bf16 bits
        if ((n16 & 1) == 0) {
          uint32_t pack = lo | (partner << 16);   // little-endian: col n16 low, n16+1 high
          uint32_t* p = (uint32_t*)(dst + (size_t)(batch0 + bi) * H_ + slice * 16 + n16);
          __hip_atomic_store(p, pack, __ATOMIC_RELAXED, __HIP_MEMORY_SCOPE_AGENT);
        }
        if (lastStep)
          out_hn[(size_t)layer * SLAB + (size_t)(batch0 + bi) * H_ + slice * 16 + n16] = hn2;
      }
      __builtin_amdgcn_s_waitcnt(0);  // stores ACKed at coherence point before flag store
    }

    __syncthreads();  // sync #2: every wave's h-stores drained (vmcnt(0) at barrier entry)

    if (r < 256 && tid == 0)
      __hip_atomic_store(&flags[(size_t)r * FL_STRIDE + bid], 1, __ATOMIC_RELAXED,
                         __HIP_MEMORY_SCOPE_AGENT);
  }
}

// ---------------- regressor: pose = LeakyReLU(Y1 @ W1^T + b1) @ W2^T + b2 ----------------
__global__ __launch_bounds__(256) void regressor_kernel(
    const uint16_t* __restrict__ Y1, const uint16_t* __restrict__ W1b,
    const float* __restrict__ b1, const float* __restrict__ W2,
    const float* __restrict__ b2, float* __restrict__ pose)
{
  __shared__ float hdn[64 * 132];
  const int t = blockIdx.x;      // timestep
  const int tid = threadIdx.x;
  const int lane = tid & 63;
  const int wid = tid >> 6;
  const int n16 = lane & 15;
  const int kg = lane >> 4;

  const uint16_t* A  = Y1 + (size_t)(t + 1) * SLAB + (size_t)(wid * 16) * H_;
  const uint16_t* ap = A + (size_t)n16 * H_ + kg * 8;
  const uint16_t* bp = W1b + (size_t)n16 * H_ + kg * 8;

  f32x4 acc[8];
  #pragma unroll
  for (int i = 0; i < 8; ++i) acc[i] = (f32x4){0,0,0,0};

  for (int ks = 0; ks < 24; ++ks) {
    bf16x8 av = *reinterpret_cast<const bf16x8*>(ap + ks * 32);
    #pragma unroll
    for (int nt = 0; nt < 8; ++nt) {
      bf16x8 bv = *reinterpret_cast<const bf16x8*>(bp + (size_t)nt * 16 * H_ + ks * 32);
      acc[nt] = mfma16(av, bv, acc[nt]);
    }
  }
  #pragma unroll
  for (int nt = 0; nt < 8; ++nt) {
    #pragma unroll
    for (int q = 0; q < 4; ++q) {
      int brow = wid * 16 + 4 * kg + q;
      int col  = nt * 16 + n16;
      float v = acc[nt][q] + b1[col];
      v = (v >= 0.0f) ? v : 0.1f * v;   // LeakyReLU(0.1)
      hdn[brow * 132 + col] = v;
    }
  }
  __syncthreads();
  for (int idx = tid; idx < 384; idx += 256) {
    int b = idx / 6, o = idx % 6;
    const float* w2r = W2 + o * 128;
    const float* hr  = &hdn[b * 132];
    float s = b2[o];
    #pragma unroll 4
    for (int c = 0; c < 128; ++c) s += hr[c] * w2r[c];
    pose[(size_t)b * (SEQ * 6) + (size_t)t * 6 + o] = s;
  }
}

extern "C" void kernel_launch(void* const* d_in, const int* in_sizes, int n_in,
                              void* d_out, int out_size, void* d_ws, size_t ws_size,
                              hipStream_t stream) {
  const float* fv  = (const float*)d_in[0];
  const float* fi  = (const float*)d_in[1];
  // d_in[2] = ts (unused by the reference)
  const float* Wih = (const float*)d_in[3];
  const float* Whh = (const float*)d_in[4];
  const float* bih = (const float*)d_in[5];
  const float* bhh = (const float*)d_in[6];
  const float* W1  = (const float*)d_in[7];
  const float* b1  = (const float*)d_in[8];
  const float* W2  = (const float*)d_in[9];
  const float* b2  = (const float*)d_in[10];
  float* out = (float*)d_out;   // [pose: 64*256*6][h_n: 2*64*768]

  char* ws = (char*)d_ws;
  size_t off = 0;
  int* flags = (int*)(ws + off);
  off += (size_t)257 * FL_STRIDE * sizeof(int);   // 263 KB
  off = (off + 255) & ~(size_t)255;
  uint16_t* Xbf = (uint16_t*)(ws + off); off += (size_t)SEQ * SLAB * 2;   // 25.2 MB
  uint16_t* Y0  = (uint16_t*)(ws + off); off += (size_t)257 * SLAB * 2;   // 25.3 MB
  uint16_t* Y1  = (uint16_t*)(ws + off); off += (size_t)257 * SLAB * 2;   // 25.3 MB
  uint16_t* W1b = (uint16_t*)(ws + off); off += (size_t)128 * H_ * 2;

  prep_kernel<<<2048, 256, 0, stream>>>(fv, fi, W1, Xbf, Y0, Y1, flags, W1b);
  gru_persist<<<192, 256, 0, stream>>>(Wih, Whh, bih, bhh, Xbf, Y0, Y1, flags, out + 98304);
  regressor_kernel<<<SEQ, 256, 0, stream>>>(Y1, W1b, b1, W2, b2, out);
}

// Round 9
// 2244.250 us; speedup vs baseline: 3.0046x; 1.3912x over previous
//
#include <hip/hip_runtime.h>
#include <stdint.h>

// PoseRNN: fused = cat(fv,fi) -> 2-layer GRU(768) -> Linear(768,128)+LeakyReLU(0.1) -> Linear(128,6)
// Persistent pipelined 2-layer GRU: 257 rounds, 192 WGs = 48 slices x 2 layers x 2 batch halves.
// Round-9: kill the SCRATCH SPILL. Round 6 introduced afr[24] consumed by a partially-unrolled
// loop -> runtime-indexed ext_vector array -> allocated in scratch (rule #20). 384B/thread/round
// = ~4.8GB HBM writes/dispatch (WRITE_SIZE 4.4-4.8GB in rounds 6-8, vs 51MB in round 1).
// Fix: fully-unrolled K loop with inline A-loads -> all fragments compile-time-indexed, VGPR-
// resident. Occupancy is LDS-bound at 1 WG/CU so the VGPR growth is free.
// Sync protocol unchanged from round 8 (proven): per-WG write-once flag vectors (no atomic-RMW
// convoy), write-through relaxed-agent h stores, s_waitcnt+syncthreads drain, zero fences.

typedef __attribute__((ext_vector_type(8))) short bf16x8;   // 8 bf16 in 4 VGPRs
typedef __attribute__((ext_vector_type(4))) short bf16x4;   // 8B
typedef __attribute__((ext_vector_type(4))) float f32x4;

#define H_   768
#define TH3  2304
#define BATCH 64
#define SEQ  256
#define SLAB (BATCH * H_)   /* 49152 elems, one timestep of h/y for all batches */
#define WROW 772            /* padded LDS row stride (ushorts): start bank 2*n16+4*kg */
#define FL_STRIDE 256       /* ints per round in the flag array (192 used, 1KB-aligned) */

__device__ __forceinline__ uint16_t f2b(float f) {
  union { float f; uint32_t u; } v; v.f = f;
  uint32_t u = v.u;
  return (uint16_t)((u + 0x7FFFu + ((u >> 16) & 1u)) >> 16);  // RNE
}

__device__ __forceinline__ f32x4 mfma16(bf16x8 a, bf16x8 b, f32x4 c) {
  return __builtin_amdgcn_mfma_f32_16x16x32_bf16(a, b, c, 0, 0, 0);
}

__device__ __forceinline__ bf16x8 ldB(const uint16_t* p) {   // two ds_read_b64 (8B-aligned rows)
  bf16x4 lo = *reinterpret_cast<const bf16x4*>(p);
  bf16x4 hi = *reinterpret_cast<const bf16x4*>(p + 4);
  bf16x8 r;
  r[0] = lo[0]; r[1] = lo[1]; r[2] = lo[2]; r[3] = lo[3];
  r[4] = hi[0]; r[5] = hi[1]; r[6] = hi[2]; r[7] = hi[3];
  return r;
}

// ---------------- prep: build time-major bf16 X, zero h0 slabs + flags, bf16 W1 -------------
__global__ __launch_bounds__(256) void prep_kernel(
    const float* __restrict__ fv, const float* __restrict__ fi,
    const float* __restrict__ W1,
    uint16_t* __restrict__ Xbf, uint16_t* __restrict__ Y0, uint16_t* __restrict__ Y1,
    int* __restrict__ flags, uint16_t* __restrict__ W1b)
{
  const int NX = SEQ * SLAB;          // 12,582,912
  const int NY = SLAB;
  const int NC = 257 * FL_STRIDE;     // 65,792 flag ints
  const int NW = 128 * H_;
  const int total = NX + 2 * NY + NC + NW;
  for (int idx = blockIdx.x * blockDim.x + threadIdx.x; idx < total;
       idx += gridDim.x * blockDim.x) {
    if (idx < NX) {
      int s = idx / SLAB;
      int rem = idx - s * SLAB;
      int b = rem / H_;
      int h = rem - b * H_;
      float val = (h < 512) ? fv[((size_t)b * SEQ + s) * 512 + h]
                            : fi[((size_t)b * SEQ + s) * 256 + (h - 512)];
      Xbf[idx] = f2b(val);
    } else if (idx < NX + 2 * NY) {
      int k = idx - NX;
      if (k < NY) Y0[k] = 0; else Y1[k - NY] = 0;
    } else if (idx < NX + 2 * NY + NC) {
      flags[idx - NX - 2 * NY] = 0;
    } else {
      int k = idx - NX - 2 * NY - NC;
      W1b[k] = f2b(W1[k]);
    }
  }
}

// ---------------- persistent pipelined 2-layer GRU ----------------
__global__ __launch_bounds__(256) void gru_persist(
    const float* __restrict__ Wih, const float* __restrict__ Whh,
    const float* __restrict__ bih, const float* __restrict__ bhh,
    const uint16_t* __restrict__ Xbf, uint16_t* __restrict__ Y0, uint16_t* __restrict__ Y1,
    int* __restrict__ flags, float* __restrict__ out_hn)
{
  __shared__ __attribute__((aligned(16))) uint16_t Wx[48 * WROW];  // 74,112 B
  __shared__ __attribute__((aligned(16))) uint16_t Wh[48 * WROW];  // 74,112 B
  __shared__ float ghbuf[32 * 48];                                 //  6,144 B
  __shared__ float hmast[32 * 16];                                 //  2,048 B
  __shared__ float bI[48];
  __shared__ float bH[48];

  const int bid   = blockIdx.x;        // 0..191
  const int slice = bid % 48;          // hidden slice: units [slice*16, slice*16+16)
  const int layer = (bid / 48) & 1;    // 0 or 1
  const int bhalf = bid / 96;          // batch half
  const int tid  = threadIdx.x;
  const int lane = tid & 63;
  const int wid  = tid >> 6;           // 4 waves
  const int mblk = wid & 1;            // 16-batch sub-block within the 32-batch half
  const int isGh = wid >> 1;           // waves 0,1 -> x-GEMM (+combine); waves 2,3 -> h-GEMM
  const int n16  = lane & 15;
  const int kg   = lane >> 4;

  // --- one-time: weight slices -> LDS bf16; rows ordered [r(16) z(16) n(16)] ---
  const float* wx_g = Wih + (size_t)layer * TH3 * H_;
  const float* wh_g = Whh + (size_t)layer * TH3 * H_;
  for (int idx = tid; idx < 48 * H_; idx += 256) {
    int lr = idx / H_;
    int c  = idx - lr * H_;
    int gate = lr >> 4, j = lr & 15;
    size_t grow = (size_t)(gate * H_ + slice * 16 + j);
    Wx[lr * WROW + c] = f2b(wx_g[grow * H_ + c]);
    Wh[lr * WROW + c] = f2b(wh_g[grow * H_ + c]);
  }
  if (tid < 48) {
    int gate = tid >> 4, j = tid & 15;
    bI[tid] = bih[layer * TH3 + gate * H_ + slice * 16 + j];
    bH[tid] = bhh[layer * TH3 + gate * H_ + slice * 16 + j];
  }
  for (int idx = tid; idx < 32 * 16; idx += 256) hmast[idx] = 0.0f;
  __syncthreads();

  const int batch0 = bhalf * 32;
  uint16_t* Yown = layer ? Y1 : Y0;

  for (int r = 0; r <= 256; ++r) {
    const bool active = (layer == 0) ? (r < 256) : (r >= 1);
    f32x4 acc0 = {0,0,0,0}, acc1 = {0,0,0,0}, acc2 = {0,0,0,0};
    uint16_t* dst = nullptr;

    if (active) {
      // layer0 step t=r:   x=Xbf[r],  h=Y0[r],   writes Y0[r+1]
      // layer1 step t=r-1: x=Y0[r],   h=Y1[r-1], writes Y1[r]
      const uint16_t* xs = (layer == 0) ? (Xbf + (size_t)r * SLAB) : (Y0 + (size_t)r * SLAB);
      const uint16_t* hs = (layer == 0) ? (Y0 + (size_t)r * SLAB) : (Y1 + (size_t)(r - 1) * SLAB);
      dst = Yown + (size_t)((layer == 0) ? (r + 1) : r) * SLAB;

      // ---- per-wave dependency poll (write-once flags; relaxed agent loads bypass L2) ----
      // gh waves need own (layer,bhalf) group's round-(r-1) flags (h slab producers).
      // x  waves of layer1 need layer0 group's round-(r-1) flags (Y0[r] producers).
      // x  waves of layer0 need nothing: Xbf is static -> run ahead of the poll.
      const int* fb = nullptr;
      if (r >= 1) {
        if (isGh)            fb = flags + (size_t)(r - 1) * FL_STRIDE + bhalf * 96 + layer * 48;
        else if (layer == 1) fb = flags + (size_t)(r - 1) * FL_STRIDE + bhalf * 96;
      }
      if (fb) {
        const int* fp = fb + (lane < 48 ? lane : 0);
        int spins = 0;
        for (;;) {
          int v = __hip_atomic_load(fp, __ATOMIC_RELAXED, __HIP_MEMORY_SCOPE_AGENT);
          if (lane >= 48) v = 1;
          if (__all(v != 0)) break;
          if (++spins > (1 << 15)) break;  // hang guard; break => absmax fail, not timeout
          __builtin_amdgcn_s_sleep(1);
        }
      }

      const uint16_t* A  = (isGh ? hs : xs) + (size_t)(batch0 + mblk * 16) * H_;
      const uint16_t* ap = A + (size_t)n16 * H_ + kg * 8;
      const uint16_t* Wl = isGh ? Wh : Wx;
      const uint16_t* bp = Wl + (size_t)n16 * WROW + kg * 8;

      // ---- GEMM: FULLY unrolled, A-loads inline -> everything compile-time-indexed,
      //      VGPR-resident (round-6's afr[24] + partial unroll put 384B/thread in scratch
      //      = 4.4GB/dispatch HBM writes; rule #20) ----
      #pragma unroll
      for (int ks = 0; ks < 24; ++ks) {
        bf16x8 av  = *reinterpret_cast<const bf16x8*>(ap + ks * 32);
        bf16x8 bv0 = ldB(bp + ks * 32);
        bf16x8 bv1 = ldB(bp + 16 * WROW + ks * 32);
        bf16x8 bv2 = ldB(bp + 32 * WROW + ks * 32);
        acc0 = mfma16(av, bv0, acc0);
        acc1 = mfma16(av, bv1, acc1);
        acc2 = mfma16(av, bv2, acc2);
      }
      if (isGh) {
        #pragma unroll
        for (int q = 0; q < 4; ++q) {
          int bi = mblk * 16 + 4 * kg + q;          // D row = 4*(lane>>4)+q
          ghbuf[bi * 48 +      n16] = acc0[q];
          ghbuf[bi * 48 + 16 + n16] = acc1[q];
          ghbuf[bi * 48 + 32 + n16] = acc2[q];
        }
      }
    }
    __syncthreads();  // sync #1: gh tiles visible to combine waves

    if (active && !isGh) {
      const bool lastStep = (layer == 0) ? (r == 255) : (r == 256);
      #pragma unroll
      for (int q = 0; q < 4; ++q) {
        int bi = mblk * 16 + 4 * kg + q;
        float ghr = ghbuf[bi * 48 +      n16] + bH[n16];
        float ghz = ghbuf[bi * 48 + 16 + n16] + bH[16 + n16];
        float ghn = ghbuf[bi * 48 + 32 + n16] + bH[32 + n16];
        float gxr = acc0[q] + bI[n16];
        float gxz = acc1[q] + bI[16 + n16];
        float gxn = acc2[q] + bI[32 + n16];
        float rg = 1.0f / (1.0f + __expf(-(gxr + ghr)));
        float zg = 1.0f / (1.0f + __expf(-(gxz + ghz)));
        float ng = tanhf(gxn + rg * ghn);
        float hv = hmast[bi * 16 + n16];
        float hn2 = (1.0f - zg) * ng + zg * hv;
        hmast[bi * 16 + n16] = hn2;
        // ---- write-through (agent, relaxed) packed dword store: no dirty L2, no fences ----
        uint32_t lo = (uint32_t)f2b(hn2);
        uint32_t partner = (uint32_t)__shfl_xor((int)lo, 1, 64);  // col n16^1's bf16 bits
        if ((n16 & 1) == 0) {
          uint32_t pack = lo | (partner << 16);   // little-endian: col n16 low, n16+1 high
          uint32_t* p = (uint32_t*)(dst + (size_t)(batch0 + bi) * H_ + slice * 16 + n16);
          __hip_atomic_store(p, pack, __ATOMIC_RELAXED, __HIP_MEMORY_SCOPE_AGENT);
        }
        if (lastStep)
          out_hn[(size_t)layer * SLAB + (size_t)(batch0 + bi) * H_ + slice * 16 + n16] = hn2;
      }
      __builtin_amdgcn_s_waitcnt(0);  // stores ACKed at coherence point before flag store
    }

    __syncthreads();  // sync #2: every wave's h-stores drained (vmcnt(0) at barrier entry)

    if (r < 256 && tid == 0)
      __hip_atomic_store(&flags[(size_t)r * FL_STRIDE + bid], 1, __ATOMIC_RELAXED,
                         __HIP_MEMORY_SCOPE_AGENT);
  }
}

// ---------------- regressor: pose = LeakyReLU(Y1 @ W1^T + b1) @ W2^T + b2 ----------------
__global__ __launch_bounds__(256) void regressor_kernel(
    const uint16_t* __restrict__ Y1, const uint16_t* __restrict__ W1b,
    const float* __restrict__ b1, const float* __restrict__ W2,
    const float* __restrict__ b2, float* __restrict__ pose)
{
  __shared__ float hdn[64 * 132];
  const int t = blockIdx.x;      // timestep
  const int tid = threadIdx.x;
  const int lane = tid & 63;
  const int wid = tid >> 6;
  const int n16 = lane & 15;
  const int kg = lane >> 4;

  const uint16_t* A  = Y1 + (size_t)(t + 1) * SLAB + (size_t)(wid * 16) * H_;
  const uint16_t* ap = A + (size_t)n16 * H_ + kg * 8;
  const uint16_t* bp = W1b + (size_t)n16 * H_ + kg * 8;

  f32x4 acc[8];
  #pragma unroll
  for (int i = 0; i < 8; ++i) acc[i] = (f32x4){0,0,0,0};

  #pragma unroll
  for (int ks = 0; ks < 24; ++ks) {
    bf16x8 av = *reinterpret_cast<const bf16x8*>(ap + ks * 32);
    #pragma unroll
    for (int nt = 0; nt < 8; ++nt) {
      bf16x8 bv = *reinterpret_cast<const bf16x8*>(bp + (size_t)nt * 16 * H_ + ks * 32);
      acc[nt] = mfma16(av, bv, acc[nt]);
    }
  }
  #pragma unroll
  for (int nt = 0; nt < 8; ++nt) {
    #pragma unroll
    for (int q = 0; q < 4; ++q) {
      int brow = wid * 16 + 4 * kg + q;
      int col  = nt * 16 + n16;
      float v = acc[nt][q] + b1[col];
      v = (v >= 0.0f) ? v : 0.1f * v;   // LeakyReLU(0.1)
      hdn[brow * 132 + col] = v;
    }
  }
  __syncthreads();
  for (int idx = tid; idx < 384; idx += 256) {
    int b = idx / 6, o = idx % 6;
    const float* w2r = W2 + o * 128;
    const float* hr  = &hdn[b * 132];
    float s = b2[o];
    #pragma unroll 4
    for (int c = 0; c < 128; ++c) s += hr[c] * w2r[c];
    pose[(size_t)b * (SEQ * 6) + (size_t)t * 6 + o] = s;
  }
}

extern "C" void kernel_launch(void* const* d_in, const int* in_sizes, int n_in,
                              void* d_out, int out_size, void* d_ws, size_t ws_size,
                              hipStream_t stream) {
  const float* fv  = (const float*)d_in[0];
  const float* fi  = (const float*)d_in[1];
  // d_in[2] = ts (unused by the reference)
  const float* Wih = (const float*)d_in[3];
  const float* Whh = (const float*)d_in[4];
  const float* bih = (const float*)d_in[5];
  const float* bhh = (const float*)d_in[6];
  const float* W1  = (const float*)d_in[7];
  const float* b1  = (const float*)d_in[8];
  const float* W2  = (const float*)d_in[9];
  const float* b2  = (const float*)d_in[10];
  float* out = (float*)d_out;   // [pose: 64*256*6][h_n: 2*64*768]

  char* ws = (char*)d_ws;
  size_t off = 0;
  int* flags = (int*)(ws + off);
  off += (size_t)257 * FL_STRIDE * sizeof(int);   // 263 KB
  off = (off + 255) & ~(size_t)255;
  uint16_t* Xbf = (uint16_t*)(ws + off); off += (size_t)SEQ * SLAB * 2;   // 25.2 MB
  uint16_t* Y0  = (uint16_t*)(ws + off); off += (size_t)257 * SLAB * 2;   // 25.3 MB
  uint16_t* Y1  = (uint16_t*)(ws + off); off += (size_t)257 * SLAB * 2;   // 25.3 MB
  uint16_t* W1b = (uint16_t*)(ws + off); off += (size_t)128 * H_ * 2;

  prep_kernel<<<2048, 256, 0, stream>>>(fv, fi, W1, Xbf, Y0, Y1, flags, W1b);
  gru_persist<<<192, 256, 0, stream>>>(Wih, Whh, bih, bhh, Xbf, Y0, Y1, flags, out + 98304);
  regressor_kernel<<<SEQ, 256, 0, stream>>>(Y1, W1b, b1, W2, b2, out);
}